// Round 13
// baseline (127.853 us; speedup 1.0000x reference)
//
#include <hip/hip_runtime.h>
#include <hip/hip_bf16.h>

// attention_11269994185437: B=4, C=256, CQK=32, H=W=64 -> N=4096
// out = gamma * (V @ P) + x,  P[n,m] = softmax over m of S[n,m], S = Q^T K.
// Qt pre-scaled by L2E: S' = L2E*S. cbias[b][n] = -log2(sum_m exp2(S'[n,m])).
// k_rowstats: S^T = K*Q^T -> reduction axis in-lane, one scalar acc/lane.
// k_attn_out: out^T = E^T * V^T. 768 threads: waves 0-3 producers (m-frag w),
//   waves 4-11 consumers (32-c slice, acc[4]=64 regs) -> 3 waves/SIMD.
//   Producer computes S one interval AHEAD (Q staged 2 ahead, qbuf 3-deep),
//   so E(j) is pure register VALU. 2-tile intervals, bf16 partials.
// k_comb: sum bf16 partials, LDS-transpose [m][c]->[c][m], out = g*sum + x.

#define NB 4
#define CC 256
#define NN 4096
#define L2E 1.44269504088896340f

typedef short  short4v  __attribute__((ext_vector_type(4)));
typedef short  short8v  __attribute__((ext_vector_type(8)));
typedef __bf16 bf16x8   __attribute__((ext_vector_type(8)));
typedef float  f32x4    __attribute__((ext_vector_type(4)));
typedef float  f32x16   __attribute__((ext_vector_type(16)));
typedef unsigned long u64x2 __attribute__((ext_vector_type(2)));
typedef unsigned int u32;

#define AS1 __attribute__((address_space(1)))
#define AS3 __attribute__((address_space(3)))

static __device__ __forceinline__ void gload16(const void* g, void* l) {
  __builtin_amdgcn_global_load_lds((const AS1 u32*)g, (AS3 u32*)l, 16, 0, 0);
}

static __device__ __forceinline__ unsigned short f2bf(float f) {
  union { __bf16 h; unsigned short u; } v; v.h = (__bf16)f; return v.u;
}
static __device__ __forceinline__ float bf2f(unsigned short u) {
  union { unsigned u; float f; } v; v.u = (u32)u << 16; return v.f;
}

union FragU { short8v s; bf16x8 b; unsigned u[4]; };

static __device__ __forceinline__ bf16x8 ld_frag(const unsigned short* p) {
  FragU u; u.s = *(const short8v*)p; return u.b;
}

static __device__ __forceinline__ f32x16 zero16() {
  f32x16 v;
#pragma unroll
  for (int i = 0; i < 16; ++i) v[i] = 0.0f;
  return v;
}

static __device__ __forceinline__ f32x16 mfma32(bf16x8 a, bf16x8 b, f32x16 c) {
  return __builtin_amdgcn_mfma_f32_32x32x16_bf16(a, b, c, 0, 0, 0);
}

// ---------------- Kernel 0: W -> bf16 row-major [320][256] ----------------
__global__ __launch_bounds__(256) void k_wcvt(
    const float* __restrict__ Wq, const float* __restrict__ Wk,
    const float* __restrict__ Wv, unsigned short* __restrict__ Wb)
{
  const int i4 = blockIdx.x * 256 + threadIdx.x;     // 80 blocks
  const int e = i4 * 4;
  const int row = e >> 8, c = e & 255;
  const float* src = (row < 32) ? (Wq + row * 256 + c)
                   : (row < 64) ? (Wk + (row - 32) * 256 + c)
                                : (Wv + (row - 64) * 256 + c);
  f32x4 v = *(const f32x4*)src;
  short4v s;
#pragma unroll
  for (int j = 0; j < 4; ++j) s[j] = (short)f2bf(v[j]);
  *(short4v*)(Wb + e) = s;
}

// ---------------- Kernel 1: QKV projection --------------------------------
__global__ __launch_bounds__(256) void k_proj(
    const float* __restrict__ x, const unsigned short* __restrict__ Wb,
    const float* __restrict__ bq, const float* __restrict__ bk,
    const float* __restrict__ bv,
    unsigned short* __restrict__ Qt, unsigned short* __restrict__ Kt,
    unsigned char* __restrict__ V8)
{
  __shared__ unsigned short xs[32][268];   // xs[n_local][c]
  const int t = threadIdx.x;
  const int b = blockIdx.y;
  const int n0 = blockIdx.x * 32;
  const int w = t >> 6, l = t & 63, h = l >> 5, col = l & 31;

  const float* xb = x + (size_t)b * CC * NN;
  {
    const int c_off = t >> 3, nl = 4 * (t & 7);
#pragma unroll
    for (int c0 = 0; c0 < CC; c0 += 32) {
      int c = c0 + c_off;
      f32x4 v4 = *(const f32x4*)(xb + (size_t)c * NN + n0 + nl);
#pragma unroll
      for (int j = 0; j < 4; ++j) xs[nl + j][c] = f2bf(v4[j]);
    }
  }
  __syncthreads();

  for (int f = w; f < 10; f += 4) {
    const float* bsrc; int rowbase; int mode; int wrow;
    if (f == 0)      { bsrc = bq; rowbase = 0;            mode = 0; wrow = 0; }
    else if (f == 1) { bsrc = bk; rowbase = 0;            mode = 1; wrow = 32; }
    else             { bsrc = bv; rowbase = (f - 2) * 32; mode = 2; wrow = 64 + rowbase; }

    f32x16 acc0 = zero16();
    const unsigned short* wr = Wb + (size_t)(wrow + col) * 256 + 8 * h;

#pragma unroll
    for (int k0 = 0; k0 < CC; k0 += 16) {
      FragU a;
      a.s = *(const short8v*)(wr + k0);
      const unsigned short* p0 = &xs[col][k0 + 8 * h];
      FragU b0;
      short4v t0a = *(const short4v*)p0, t0b = *(const short4v*)(p0 + 4);
#pragma unroll
      for (int j = 0; j < 4; ++j) { b0.s[j] = t0a[j]; b0.s[4 + j] = t0b[j]; }
      acc0 = mfma32(a.b, b0.b, acc0);
    }

    const int n = n0 + col;
#pragma unroll
    for (int q = 0; q < 4; ++q) {
      f32x4 bias4 = *(const f32x4*)(bsrc + rowbase + 8 * q + 4 * h);
      float vals[4];
#pragma unroll
      for (int i = 0; i < 4; ++i) vals[i] = acc0[4 * q + i] + bias4[i];
      if (mode == 2) {
        // V8[b][n>>4][(n&15)>>3][c][n&7]
        const size_t tb = (((size_t)b * (NN >> 4) + (n >> 4)) * 2 + ((n >> 3) & 1)) * CC * 8
                          + (n & 7);
        u32 w01 = __builtin_amdgcn_cvt_pk_fp8_f32(vals[0], vals[1], 0, false);
        u32 w23 = __builtin_amdgcn_cvt_pk_fp8_f32(vals[2], vals[3], 0, false);
        const int cb0 = rowbase + 8 * q + 4 * h;
        V8[tb + (size_t)(cb0 + 0) * 8] = (unsigned char)(w01 & 0xff);
        V8[tb + (size_t)(cb0 + 1) * 8] = (unsigned char)((w01 >> 8) & 0xff);
        V8[tb + (size_t)(cb0 + 2) * 8] = (unsigned char)(w23 & 0xff);
        V8[tb + (size_t)(cb0 + 3) * 8] = (unsigned char)((w23 >> 8) & 0xff);
      } else {
        unsigned short* dst = (mode == 0) ? Qt : Kt;
        const float scale = (mode == 0) ? L2E : 1.0f;   // fold L2E into Q
        short4v s4;
#pragma unroll
        for (int i = 0; i < 4; ++i) s4[i] = (short)f2bf(vals[i] * scale);
        *(short4v*)(dst + ((size_t)b * NN + n) * 32 + 8 * q + 4 * h) = s4;
      }
    }
  }
}

// ---------------- Kernel 2: row sums -> cbias (transposed MFMA) -----------
__global__ __launch_bounds__(256) void k_rowstats(
    const unsigned short* __restrict__ Qt, const unsigned short* __restrict__ Kt,
    float* __restrict__ cbias)
{
  __shared__ float ssum[4][32];
  const int t = threadIdx.x;
  const int w = t >> 6, l = t & 63, h = l >> 5, col = l & 31;
  const int b = blockIdx.y;
  const int n0 = blockIdx.x * 32;
  const unsigned short* Qb = Qt + (size_t)b * NN * 32;
  const unsigned short* Kb = Kt + (size_t)b * NN * 32;

  bf16x8 bq0 = ld_frag(Qb + (size_t)(n0 + col) * 32 + 8 * h);
  bf16x8 bq1 = ld_frag(Qb + (size_t)(n0 + col) * 32 + 16 + 8 * h);

  float acc = 0.0f;
  const int mbase = w * (NN / 4);
#pragma unroll 2
  for (int mt = 0; mt < 32; ++mt) {
    const int m0 = mbase + mt * 32;
    bf16x8 ak0 = ld_frag(Kb + (size_t)(m0 + col) * 32 + 8 * h);
    bf16x8 ak1 = ld_frag(Kb + (size_t)(m0 + col) * 32 + 16 + 8 * h);
    f32x16 S = zero16();
    S = mfma32(ak0, bq0, S);
    S = mfma32(ak1, bq1, S);
    float p0 = 0.0f, p1 = 0.0f, p2 = 0.0f, p3 = 0.0f;
#pragma unroll
    for (int r = 0; r < 4; ++r) {
      p0 += __builtin_amdgcn_exp2f(S[r]);
      p1 += __builtin_amdgcn_exp2f(S[4 + r]);
      p2 += __builtin_amdgcn_exp2f(S[8 + r]);
      p3 += __builtin_amdgcn_exp2f(S[12 + r]);
    }
    acc += (p0 + p1) + (p2 + p3);
  }
  acc += __shfl_xor(acc, 32);

  if (l < 32) ssum[w][l] = acc;
  __syncthreads();

  if (t < 32) {
    float s = (ssum[0][t] + ssum[1][t]) + (ssum[2][t] + ssum[3][t]);
    cbias[(size_t)b * NN + n0 + t] = -__builtin_amdgcn_logf(s);
  }
}

// ---------------- Kernel 3: out^T = E^T * V^T, 4P+8C, S-ahead -------------
// grid 128*nsplit (XCD-swizzled), 12 waves (768 thr). m-tile 128, all 256 c.
// waves 0-3: producer m-frag w. waves 4-11: consumer 32-c slice (w-4)*32.
// Interval j = tiles {2j, 2j+1}. Producer: S(j+1) MFMAs issued first, then
// E(j) from registers (computed last interval). Q staged 2 intervals ahead.
__global__ __launch_bounds__(768) void k_attn_out(
    const unsigned short* __restrict__ Qt, const unsigned short* __restrict__ Kt,
    const unsigned char* __restrict__ V8,
    const float* __restrict__ cbias,
    unsigned short* __restrict__ pout,
    int nsplit, int nlen)
{
  __shared__ __align__(16) char qbuf[3][2][2048];  // [buf][u] Q frag-linear
  __shared__ __align__(16) char vbuf[3][2][8192];  // [buf][u] V [t16][kh][c][8]
  __shared__ __align__(16) char ebuf[2][2][4096];  // [buf][u] E A-frags [mf][lane][16B]

  const int wg = (int)blockIdx.x;
  const int chunk = (int)gridDim.x >> 3;           // blocks per XCD (bijective)
  const int id2 = (wg & 7) * chunk + (wg >> 3);
  const int per_b = 32 * nsplit;                   // m-tiles(128) per batch * nsplit
  const int b = id2 / per_b;
  const int rem = id2 - b * per_b;
  const int ns = rem >> 5;
  const int m0 = (rem & 31) * 128;
  const int nbeg = ns * nlen;

  const int t = threadIdx.x;
  const int w = t >> 6, l = t & 63, h = l >> 5, col = l & 31;
  const bool isP = (w < 4);
  const int mfp = w & 3;                           // producer m-frag
  const int ccons = (w - 4) * 32;                  // consumer c-slice

  const unsigned short* Kb = Kt + (size_t)b * NN * 32;
  const float* cb = cbias + (size_t)b * NN + nbeg;

  // producer K fragments (B operand of S), loop-invariant
  bf16x8 bk0 = ld_frag(Kb + (size_t)(m0 + 32 * mfp + col) * 32 + 8 * h);
  bf16x8 bk1 = ld_frag(Kb + (size_t)(m0 + 32 * mfp + col) * 32 + 16 + 8 * h);

  // Q staging (producers, lanes 0-31): chunk = w*32 + (l&31), dest w*512.
  // global byte = (l&31)*64 + (w&1)*16 + (w>>1)*32
  const size_t gqoff = (size_t)((l & 31) * 64 + (w & 1) * 16 + (w >> 1) * 32);
  const char* qsrc = (const char*)Qt + ((size_t)b * NN + nbeg) * 64 + gqoff;
  // V staging (consumers, all lanes): chunk = (w-4)*64 + l, dest (w-4)*1024.
  const char* vsrc = (const char*)V8 + ((size_t)b * (NN >> 4) + (nbeg >> 4)) * 4096
                     + (size_t)(w - 4) * 1024 + (size_t)l * 16;

  f32x16 acc[4];
#pragma unroll
  for (int mf = 0; mf < 4; ++mf) acc[mf] = zero16();

  f32x16 Ssave[2], Snew[2];

  const int J = nlen >> 6;                          // intervals of 64 n

  // ---- prologue: stage Q(0),Q(1), V(0) ----
  if (isP) {
    if (l < 32) {
      gload16(qsrc, &qbuf[0][0][w * 512]);
      gload16(qsrc + 2048, &qbuf[0][1][w * 512]);
      gload16(qsrc + 2 * 2048, &qbuf[1][0][w * 512]);
      gload16(qsrc + 3 * 2048, &qbuf[1][1][w * 512]);
    }
  } else {
    gload16(vsrc, &vbuf[0][0][(w - 4) * 1024]);
    gload16(vsrc + 8192, &vbuf[0][1][(w - 4) * 1024]);
  }
  __syncthreads();

  // ---- S for interval 0 ----
  if (isP) {
#pragma unroll
    for (int u = 0; u < 2; ++u) {
      const char* qb = &qbuf[0][u][0];
      FragU fq0, fq1;
      fq0.s = *(const short8v*)(qb + l * 16);
      fq1.s = *(const short8v*)(qb + 1024 + l * 16);
      f32x16 S = zero16();
      S = mfma32(fq0.b, bk0, S);
      Ssave[u] = mfma32(fq1.b, bk1, S);
    }
  }

  for (int j = 0; j <= J; ++j) {
    // ---- stage Q(j+2) and V(j+1) ----
    if (isP) {
      if (j + 2 < J && l < 32) {
        const size_t qoff = (size_t)(2 * (j + 2)) * 2048;
        const int qs = (j + 2) % 3;
        gload16(qsrc + qoff, &qbuf[qs][0][w * 512]);
        gload16(qsrc + qoff + 2048, &qbuf[qs][1][w * 512]);
      }
      if (j < J) {
        // ---- producer: issue S(j+1) MFMAs, then E(j) from registers ----
        if (j + 1 < J) {
          const int qs = (j + 1) % 3;
#pragma unroll
          for (int u = 0; u < 2; ++u) {
            const char* qb = &qbuf[qs][u][0];
            FragU fq0, fq1;
            fq0.s = *(const short8v*)(qb + l * 16);
            fq1.s = *(const short8v*)(qb + 1024 + l * 16);
            f32x16 S = zero16();
            S = mfma32(fq0.b, bk0, S);
            Snew[u] = mfma32(fq1.b, bk1, S);
          }
        }
#pragma unroll
        for (int u = 0; u < 2; ++u) {
          float e[16];
          const float* cbi = cb + (2 * j + u) * 32;
#pragma unroll
          for (int q = 0; q < 4; ++q) {
            f32x4 cb4 = *(const f32x4*)(cbi + 8 * q + 4 * h);
#pragma unroll
            for (int i = 0; i < 4; ++i)
              e[4 * q + i] = __builtin_amdgcn_exp2f(Ssave[u][4 * q + i] + cb4[i]);
          }
          u32 wA = __builtin_amdgcn_cvt_pk_fp8_f32(e[0], e[1], 0, false);
          wA = __builtin_amdgcn_cvt_pk_fp8_f32(e[2], e[3], wA, true);
          u32 wB = __builtin_amdgcn_cvt_pk_fp8_f32(e[4], e[5], 0, false);
          wB = __builtin_amdgcn_cvt_pk_fp8_f32(e[6], e[7], wB, true);
          u32 wC = __builtin_amdgcn_cvt_pk_fp8_f32(e[8], e[9], 0, false);
          wC = __builtin_amdgcn_cvt_pk_fp8_f32(e[10], e[11], wC, true);
          u32 wD = __builtin_amdgcn_cvt_pk_fp8_f32(e[12], e[13], 0, false);
          wD = __builtin_amdgcn_cvt_pk_fp8_f32(e[14], e[15], wD, true);
          asm("v_permlane32_swap_b32 %0, %1" : "+v"(wA), "+v"(wB));
          asm("v_permlane32_swap_b32 %0, %1" : "+v"(wC), "+v"(wD));
          u64x2 ev;
          ev[0] = ((unsigned long)wB << 32) | wA;   // A0: n' 0..15
          ev[1] = ((unsigned long)wD << 32) | wC;   // A1: n' 16..31
          *(u64x2*)(&ebuf[j & 1][u][mfp * 1024 + l * 16]) = ev;
        }
        if (j + 1 < J) { Ssave[0] = Snew[0]; Ssave[1] = Snew[1]; }
      }
    } else {
      if (j + 1 < J) {
        const size_t voff = (size_t)(2 * (j + 1)) * 8192;
        const int vs = (j + 1) % 3;
        gload16(vsrc + voff, &vbuf[vs][0][(w - 4) * 1024]);
        gload16(vsrc + voff + 8192, &vbuf[vs][1][(w - 4) * 1024]);
      }
      if (j > 0) {
        // ---- consumer: PV for interval j-1 ----
        const int pv = (j + 2) % 3;                 // == (j-1) % 3
        __builtin_amdgcn_s_setprio(1);
#pragma unroll
        for (int u = 0; u < 2; ++u) {
          const char* vb = &vbuf[pv][u][h * 2048 + (ccons + col) * 8];
          long v0 = *(const long*)(vb);              // t16=0
          long v1 = *(const long*)(vb + 4096);       // t16=1
          const char* eb = &ebuf[(j - 1) & 1][u][l * 16];
          u64x2 ev0 = *(const u64x2*)(eb);
          u64x2 ev1 = *(const u64x2*)(eb + 1024);
          u64x2 ev2 = *(const u64x2*)(eb + 2048);
          u64x2 ev3 = *(const u64x2*)(eb + 3072);
          acc[0] = __builtin_amdgcn_mfma_f32_32x32x16_fp8_fp8((long)ev0[0], v0, acc[0], 0, 0, 0);
          acc[1] = __builtin_amdgcn_mfma_f32_32x32x16_fp8_fp8((long)ev1[0], v0, acc[1], 0, 0, 0);
          acc[2] = __builtin_amdgcn_mfma_f32_32x32x16_fp8_fp8((long)ev2[0], v0, acc[2], 0, 0, 0);
          acc[3] = __builtin_amdgcn_mfma_f32_32x32x16_fp8_fp8((long)ev3[0], v0, acc[3], 0, 0, 0);
          acc[0] = __builtin_amdgcn_mfma_f32_32x32x16_fp8_fp8((long)ev0[1], v1, acc[0], 0, 0, 0);
          acc[1] = __builtin_amdgcn_mfma_f32_32x32x16_fp8_fp8((long)ev1[1], v1, acc[1], 0, 0, 0);
          acc[2] = __builtin_amdgcn_mfma_f32_32x32x16_fp8_fp8((long)ev2[1], v1, acc[2], 0, 0, 0);
          acc[3] = __builtin_amdgcn_mfma_f32_32x32x16_fp8_fp8((long)ev3[1], v1, acc[3], 0, 0, 0);
        }
        __builtin_amdgcn_s_setprio(0);
      }
    }

    if (j < J) __syncthreads();
  }

  // ---- consumer epilogue: write bf16 D tiles [m][c]-major ----
  if (!isP) {
    unsigned short* pb = pout + (((size_t)ns * NB + b) * NN + m0) * CC + ccons;
#pragma unroll
    for (int mf = 0; mf < 4; ++mf)
#pragma unroll
      for (int r = 0; r < 16; ++r) {
        int mloc = 32 * mf + (r & 3) + 8 * (r >> 2) + 4 * h;
        pb[(size_t)mloc * CC + col] = f2bf(acc[mf][r]);
      }
  }
}

// ---------------- Kernel 4: combine + transpose + residual ----------------
__global__ __launch_bounds__(256) void k_comb(
    const unsigned short* __restrict__ pout, const float* __restrict__ x,
    const float* __restrict__ gamma, float* __restrict__ out, int nsplit)
{
  __shared__ float ld[64][65];
  const size_t STRIDE = (size_t)NB * CC * NN;
  const int t = threadIdx.x;
  const int m0 = blockIdx.x * 64, c0 = blockIdx.y * 64, b = blockIdx.z;
  const int ci = t & 63, mo = t >> 6;

  const unsigned short* pb = pout + ((size_t)b * NN + m0) * CC + c0;
#pragma unroll
  for (int rep = 0; rep < 16; ++rep) {
    const int mi = 4 * rep + mo;
    float s = bf2f(pb[(size_t)mi * CC + ci]);
    for (int ns = 1; ns < nsplit; ++ns)
      s += bf2f(pb[ns * STRIDE + (size_t)mi * CC + ci]);
    ld[mi][ci] = s;
  }
  __syncthreads();

  const float g = gamma[0];
  const int mi2 = t & 63;
#pragma unroll
  for (int rep = 0; rep < 16; ++rep) {
    const int cj = 4 * rep + mo;
    const size_t idx = ((size_t)b * CC + c0 + cj) * NN + m0 + mi2;
    out[idx] = g * ld[mi2][cj] + x[idx];
  }
}

// ---------------- launch ---------------------------------------------------
extern "C" void kernel_launch(void* const* d_in, const int* in_sizes, int n_in,
                              void* d_out, int out_size, void* d_ws, size_t ws_size,
                              hipStream_t stream) {
  const float* x     = (const float*)d_in[0];
  const float* Wq    = (const float*)d_in[1];
  const float* bq    = (const float*)d_in[2];
  const float* Wk    = (const float*)d_in[3];
  const float* bk    = (const float*)d_in[4];
  const float* Wv    = (const float*)d_in[5];
  const float* bv    = (const float*)d_in[6];
  const float* gamma = (const float*)d_in[7];
  float* out = (float*)d_out;

  char* ws = (char*)d_ws;
  unsigned short* Qt = (unsigned short*)(ws);                      // 1 MB
  unsigned short* Kt = (unsigned short*)(ws + (1u << 20));         // 1 MB
  unsigned char*  V8 = (unsigned char*)(ws + (2u << 20));          // 4 MB
  unsigned short* Wb = (unsigned short*)(ws + (6u << 20));         // 160 KB
  float* cbias = (float*)(ws + (10u << 20) + (2u << 18));          // 64 KB
  const size_t POUT_OFF = (11u << 20);
  unsigned short* pout = (unsigned short*)(ws + POUT_OFF);
  const size_t PART_BYTES = (size_t)NB * CC * NN * 2;              // 8.4 MB (bf16)

  int nsplit = (ws_size >= POUT_OFF + 2 * PART_BYTES) ? 2 : 1;

  k_wcvt<<<dim3(80), 256, 0, stream>>>(Wq, Wk, Wv, Wb);
  k_proj<<<dim3(NN / 32, NB), 256, 0, stream>>>(x, Wb, bq, bk, bv, Qt, Kt, V8);
  k_rowstats<<<dim3(NN / 32, NB), 256, 0, stream>>>(Qt, Kt, cbias);
  k_attn_out<<<dim3(128 * nsplit), 768, 0, stream>>>(
      Qt, Kt, V8, cbias, pout, nsplit, NN / nsplit);
  k_comb<<<dim3(NN / 64, CC / 64, NB), 256, 0, stream>>>(pout, x, gamma, out, nsplit);
}

// Round 14
// 114.353 us; speedup vs baseline: 1.1181x; 1.1181x over previous
//
#include <hip/hip_runtime.h>
#include <hip/hip_bf16.h>

// attention_11269994185437: B=4, C=256, CQK=32, H=W=64 -> N=4096
// out = gamma * (V @ P) + x,  P[n,m] = softmax over m of S[n,m], S = Q^T K.
// Qt pre-scaled by L2E: S' = L2E*S. cbias[b][n] = -log2(sum_m exp2(S'[n,m])).
// k_rowstats: S^T = K*Q^T -> reduction axis in-lane, one scalar acc/lane.
// k_attn_out: out^T = E^T * V^T. 384 threads (2 producers + 4 consumers),
//   m-tile 64, acc[2][2]=64 regs, LDS 64 KB -> 2 independent blocks/CU
//   (uncorrelated barrier phases). 2-tile intervals, bf16 partials.
// k_comb: sum bf16 partials, LDS-transpose [m][c]->[c][m], out = g*sum + x.

#define NB 4
#define CC 256
#define NN 4096
#define L2E 1.44269504088896340f

typedef short  short4v  __attribute__((ext_vector_type(4)));
typedef short  short8v  __attribute__((ext_vector_type(8)));
typedef __bf16 bf16x8   __attribute__((ext_vector_type(8)));
typedef float  f32x4    __attribute__((ext_vector_type(4)));
typedef float  f32x16   __attribute__((ext_vector_type(16)));
typedef unsigned long u64x2 __attribute__((ext_vector_type(2)));
typedef unsigned int u32;

#define AS1 __attribute__((address_space(1)))
#define AS3 __attribute__((address_space(3)))

static __device__ __forceinline__ void gload16(const void* g, void* l) {
  __builtin_amdgcn_global_load_lds((const AS1 u32*)g, (AS3 u32*)l, 16, 0, 0);
}

static __device__ __forceinline__ unsigned short f2bf(float f) {
  union { __bf16 h; unsigned short u; } v; v.h = (__bf16)f; return v.u;
}
static __device__ __forceinline__ float bf2f(unsigned short u) {
  union { unsigned u; float f; } v; v.u = (u32)u << 16; return v.f;
}

union FragU { short8v s; bf16x8 b; unsigned u[4]; };

static __device__ __forceinline__ bf16x8 ld_frag(const unsigned short* p) {
  FragU u; u.s = *(const short8v*)p; return u.b;
}

static __device__ __forceinline__ f32x16 zero16() {
  f32x16 v;
#pragma unroll
  for (int i = 0; i < 16; ++i) v[i] = 0.0f;
  return v;
}

static __device__ __forceinline__ f32x16 mfma32(bf16x8 a, bf16x8 b, f32x16 c) {
  return __builtin_amdgcn_mfma_f32_32x32x16_bf16(a, b, c, 0, 0, 0);
}

// ---------------- Kernel 0: W -> bf16 row-major [320][256] ----------------
__global__ __launch_bounds__(256) void k_wcvt(
    const float* __restrict__ Wq, const float* __restrict__ Wk,
    const float* __restrict__ Wv, unsigned short* __restrict__ Wb)
{
  const int i4 = blockIdx.x * 256 + threadIdx.x;     // 80 blocks
  const int e = i4 * 4;
  const int row = e >> 8, c = e & 255;
  const float* src = (row < 32) ? (Wq + row * 256 + c)
                   : (row < 64) ? (Wk + (row - 32) * 256 + c)
                                : (Wv + (row - 64) * 256 + c);
  f32x4 v = *(const f32x4*)src;
  short4v s;
#pragma unroll
  for (int j = 0; j < 4; ++j) s[j] = (short)f2bf(v[j]);
  *(short4v*)(Wb + e) = s;
}

// ---------------- Kernel 1: QKV projection --------------------------------
__global__ __launch_bounds__(256) void k_proj(
    const float* __restrict__ x, const unsigned short* __restrict__ Wb,
    const float* __restrict__ bq, const float* __restrict__ bk,
    const float* __restrict__ bv,
    unsigned short* __restrict__ Qt, unsigned short* __restrict__ Kt,
    unsigned char* __restrict__ V8)
{
  __shared__ unsigned short xs[32][268];   // xs[n_local][c]
  const int t = threadIdx.x;
  const int b = blockIdx.y;
  const int n0 = blockIdx.x * 32;
  const int w = t >> 6, l = t & 63, h = l >> 5, col = l & 31;

  const float* xb = x + (size_t)b * CC * NN;
  {
    const int c_off = t >> 3, nl = 4 * (t & 7);
#pragma unroll
    for (int c0 = 0; c0 < CC; c0 += 32) {
      int c = c0 + c_off;
      f32x4 v4 = *(const f32x4*)(xb + (size_t)c * NN + n0 + nl);
#pragma unroll
      for (int j = 0; j < 4; ++j) xs[nl + j][c] = f2bf(v4[j]);
    }
  }
  __syncthreads();

  for (int f = w; f < 10; f += 4) {
    const float* bsrc; int rowbase; int mode; int wrow;
    if (f == 0)      { bsrc = bq; rowbase = 0;            mode = 0; wrow = 0; }
    else if (f == 1) { bsrc = bk; rowbase = 0;            mode = 1; wrow = 32; }
    else             { bsrc = bv; rowbase = (f - 2) * 32; mode = 2; wrow = 64 + rowbase; }

    f32x16 acc0 = zero16();
    const unsigned short* wr = Wb + (size_t)(wrow + col) * 256 + 8 * h;

#pragma unroll
    for (int k0 = 0; k0 < CC; k0 += 16) {
      FragU a;
      a.s = *(const short8v*)(wr + k0);
      const unsigned short* p0 = &xs[col][k0 + 8 * h];
      FragU b0;
      short4v t0a = *(const short4v*)p0, t0b = *(const short4v*)(p0 + 4);
#pragma unroll
      for (int j = 0; j < 4; ++j) { b0.s[j] = t0a[j]; b0.s[4 + j] = t0b[j]; }
      acc0 = mfma32(a.b, b0.b, acc0);
    }

    const int n = n0 + col;
#pragma unroll
    for (int q = 0; q < 4; ++q) {
      f32x4 bias4 = *(const f32x4*)(bsrc + rowbase + 8 * q + 4 * h);
      float vals[4];
#pragma unroll
      for (int i = 0; i < 4; ++i) vals[i] = acc0[4 * q + i] + bias4[i];
      if (mode == 2) {
        // V8[b][n>>4][(n&15)>>3][c][n&7]
        const size_t tb = (((size_t)b * (NN >> 4) + (n >> 4)) * 2 + ((n >> 3) & 1)) * CC * 8
                          + (n & 7);
        u32 w01 = __builtin_amdgcn_cvt_pk_fp8_f32(vals[0], vals[1], 0, false);
        u32 w23 = __builtin_amdgcn_cvt_pk_fp8_f32(vals[2], vals[3], 0, false);
        const int cb0 = rowbase + 8 * q + 4 * h;
        V8[tb + (size_t)(cb0 + 0) * 8] = (unsigned char)(w01 & 0xff);
        V8[tb + (size_t)(cb0 + 1) * 8] = (unsigned char)((w01 >> 8) & 0xff);
        V8[tb + (size_t)(cb0 + 2) * 8] = (unsigned char)(w23 & 0xff);
        V8[tb + (size_t)(cb0 + 3) * 8] = (unsigned char)((w23 >> 8) & 0xff);
      } else {
        unsigned short* dst = (mode == 0) ? Qt : Kt;
        const float scale = (mode == 0) ? L2E : 1.0f;   // fold L2E into Q
        short4v s4;
#pragma unroll
        for (int i = 0; i < 4; ++i) s4[i] = (short)f2bf(vals[i] * scale);
        *(short4v*)(dst + ((size_t)b * NN + n) * 32 + 8 * q + 4 * h) = s4;
      }
    }
  }
}

// ---------------- Kernel 2: row sums -> cbias (transposed MFMA) -----------
__global__ __launch_bounds__(256) void k_rowstats(
    const unsigned short* __restrict__ Qt, const unsigned short* __restrict__ Kt,
    float* __restrict__ cbias)
{
  __shared__ float ssum[4][32];
  const int t = threadIdx.x;
  const int w = t >> 6, l = t & 63, h = l >> 5, col = l & 31;
  const int b = blockIdx.y;
  const int n0 = blockIdx.x * 32;
  const unsigned short* Qb = Qt + (size_t)b * NN * 32;
  const unsigned short* Kb = Kt + (size_t)b * NN * 32;

  bf16x8 bq0 = ld_frag(Qb + (size_t)(n0 + col) * 32 + 8 * h);
  bf16x8 bq1 = ld_frag(Qb + (size_t)(n0 + col) * 32 + 16 + 8 * h);

  float acc = 0.0f;
  const int mbase = w * (NN / 4);
#pragma unroll 2
  for (int mt = 0; mt < 32; ++mt) {
    const int m0 = mbase + mt * 32;
    bf16x8 ak0 = ld_frag(Kb + (size_t)(m0 + col) * 32 + 8 * h);
    bf16x8 ak1 = ld_frag(Kb + (size_t)(m0 + col) * 32 + 16 + 8 * h);
    f32x16 S = zero16();
    S = mfma32(ak0, bq0, S);
    S = mfma32(ak1, bq1, S);
    float p0 = 0.0f, p1 = 0.0f, p2 = 0.0f, p3 = 0.0f;
#pragma unroll
    for (int r = 0; r < 4; ++r) {
      p0 += __builtin_amdgcn_exp2f(S[r]);
      p1 += __builtin_amdgcn_exp2f(S[4 + r]);
      p2 += __builtin_amdgcn_exp2f(S[8 + r]);
      p3 += __builtin_amdgcn_exp2f(S[12 + r]);
    }
    acc += (p0 + p1) + (p2 + p3);
  }
  acc += __shfl_xor(acc, 32);

  if (l < 32) ssum[w][l] = acc;
  __syncthreads();

  if (t < 32) {
    float s = (ssum[0][t] + ssum[1][t]) + (ssum[2][t] + ssum[3][t]);
    cbias[(size_t)b * NN + n0 + t] = -__builtin_amdgcn_logf(s);
  }
}

// ---------------- Kernel 3: out^T = E^T * V^T, 2P+4C, m-tile 64 -----------
// grid NB*64*nsplit (XCD-swizzled), 6 waves (384 thr), LDS 64 KB ->
// 2 blocks/CU with independent barrier phases.
// waves 0-1: producer m-frag w. waves 2-5: consumer 64-c slice (w-2)*64.
// Interval j = tiles {2j, 2j+1}. One __syncthreads per interval.
__global__ __launch_bounds__(384) void k_attn_out(
    const unsigned short* __restrict__ Qt, const unsigned short* __restrict__ Kt,
    const unsigned char* __restrict__ V8,
    const float* __restrict__ cbias,
    unsigned short* __restrict__ pout,
    int nsplit, int nlen)
{
  __shared__ __align__(16) char qbuf[2][2][2048];  // [buf][u] Q frag-linear
  __shared__ __align__(16) char vbuf[3][2][8192];  // [buf][u] V [t16][kh][c][8]
  __shared__ __align__(16) char ebuf[2][2][2048];  // [buf][u] E A-frags [mf][lane][16B]

  const int wg = (int)blockIdx.x;
  const int chunk = (int)gridDim.x >> 3;           // blocks per XCD (bijective)
  const int id2 = (wg & 7) * chunk + (wg >> 3);
  const int per_b = 64 * nsplit;                   // m-tiles(64) per batch * nsplit
  const int b = id2 / per_b;
  const int rem = id2 - b * per_b;
  const int ns = rem >> 6;
  const int m0 = (rem & 63) * 64;
  const int nbeg = ns * nlen;

  const int t = threadIdx.x;
  const int w = t >> 6, l = t & 63, h = l >> 5, col = l & 31;
  const bool isP = (w < 2);
  const int mfp = w & 1;                           // producer m-frag
  const int ccons = (w - 2) * 64;                  // consumer c-slice base

  const unsigned short* Kb = Kt + (size_t)b * NN * 32;
  const float* cb = cbias + (size_t)b * NN + nbeg;

  // producer K fragments (B operand of S), loop-invariant
  bf16x8 bk0 = ld_frag(Kb + (size_t)(m0 + 32 * mfp + col) * 32 + 8 * h);
  bf16x8 bk1 = ld_frag(Kb + (size_t)(m0 + 32 * mfp + col) * 32 + 16 + 8 * h);

  // Q staging (producers, all 64 lanes): chunk i = w*64 + l -> LDS i*16,
  // global byte = (l&31)*64 + (l>>5)*16 + w*32.
  const size_t gqoff = (size_t)((l & 31) * 64 + (l >> 5) * 16 + w * 32);
  const char* qsrc = (const char*)Qt + ((size_t)b * NN + nbeg) * 64 + gqoff;
  // V staging (consumers): chunks cw*64+l and 256+cw*64+l (identity layout).
  const int cw = w - 2;
  const char* vsrc = (const char*)V8 + ((size_t)b * (NN >> 4) + (nbeg >> 4)) * 4096
                     + (size_t)(cw * 64 + l) * 16;

  f32x16 acc[2][2];
#pragma unroll
  for (int mf = 0; mf < 2; ++mf)
#pragma unroll
    for (int cf = 0; cf < 2; ++cf) acc[mf][cf] = zero16();

  const int J = nlen >> 6;                          // intervals of 64 n

  // ---- prologue: stage interval 0 (tiles 0,1) ----
  if (isP) {
    gload16(qsrc, &qbuf[0][0][(w * 64 + l) * 16]);
    gload16(qsrc + 2048, &qbuf[0][1][(w * 64 + l) * 16]);
  } else {
    gload16(vsrc, &vbuf[0][0][(size_t)(cw * 64 + l) * 16]);
    gload16(vsrc + 4096, &vbuf[0][0][(size_t)(cw * 64 + l) * 16 + 4096]);
    gload16(vsrc + 8192, &vbuf[0][1][(size_t)(cw * 64 + l) * 16]);
    gload16(vsrc + 8192 + 4096, &vbuf[0][1][(size_t)(cw * 64 + l) * 16 + 4096]);
  }
  __syncthreads();

  for (int j = 0; j <= J; ++j) {
    // ---- stage interval j+1 (tiles 2j+2, 2j+3) ----
    if (j + 1 < J) {
      const int qs = (j + 1) & 1, vs = (j + 1) % 3;
      if (isP) {
        const size_t qoff = (size_t)(2 * j + 2) * 2048;
        gload16(qsrc + qoff, &qbuf[qs][0][(w * 64 + l) * 16]);
        gload16(qsrc + qoff + 2048, &qbuf[qs][1][(w * 64 + l) * 16]);
      } else {
        const size_t voff = (size_t)(2 * j + 2) * 8192;
        gload16(vsrc + voff, &vbuf[vs][0][(size_t)(cw * 64 + l) * 16]);
        gload16(vsrc + voff + 4096, &vbuf[vs][0][(size_t)(cw * 64 + l) * 16 + 4096]);
        gload16(vsrc + voff + 8192, &vbuf[vs][1][(size_t)(cw * 64 + l) * 16]);
        gload16(vsrc + voff + 8192 + 4096, &vbuf[vs][1][(size_t)(cw * 64 + l) * 16 + 4096]);
      }
    }

    if (isP) {
      if (j < J) {
        // ---- producer: two independent S->E chains (tiles 2j, 2j+1) ----
#pragma unroll
        for (int u = 0; u < 2; ++u) {
          const char* qb = &qbuf[j & 1][u][0];
          FragU fq0, fq1;
          fq0.s = *(const short8v*)(qb + l * 16);
          fq1.s = *(const short8v*)(qb + 1024 + l * 16);
          f32x16 S = zero16();
          S = mfma32(fq0.b, bk0, S);
          S = mfma32(fq1.b, bk1, S);

          float e[16];
          const float* cbi = cb + (2 * j + u) * 32;
#pragma unroll
          for (int q = 0; q < 4; ++q) {
            f32x4 cb4 = *(const f32x4*)(cbi + 8 * q + 4 * h);
#pragma unroll
            for (int i = 0; i < 4; ++i)
              e[4 * q + i] = __builtin_amdgcn_exp2f(S[4 * q + i] + cb4[i]);
          }
          u32 wA = __builtin_amdgcn_cvt_pk_fp8_f32(e[0], e[1], 0, false);
          wA = __builtin_amdgcn_cvt_pk_fp8_f32(e[2], e[3], wA, true);
          u32 wB = __builtin_amdgcn_cvt_pk_fp8_f32(e[4], e[5], 0, false);
          wB = __builtin_amdgcn_cvt_pk_fp8_f32(e[6], e[7], wB, true);
          u32 wC = __builtin_amdgcn_cvt_pk_fp8_f32(e[8], e[9], 0, false);
          wC = __builtin_amdgcn_cvt_pk_fp8_f32(e[10], e[11], wC, true);
          u32 wD = __builtin_amdgcn_cvt_pk_fp8_f32(e[12], e[13], 0, false);
          wD = __builtin_amdgcn_cvt_pk_fp8_f32(e[14], e[15], wD, true);
          asm("v_permlane32_swap_b32 %0, %1" : "+v"(wA), "+v"(wB));
          asm("v_permlane32_swap_b32 %0, %1" : "+v"(wC), "+v"(wD));
          u64x2 ev;
          ev[0] = ((unsigned long)wB << 32) | wA;   // A0: n' 0..15
          ev[1] = ((unsigned long)wD << 32) | wC;   // A1: n' 16..31
          *(u64x2*)(&ebuf[j & 1][u][mfp * 1024 + l * 16]) = ev;
        }
      }
    } else {
      if (j > 0) {
        // ---- consumer: PV for interval j-1, dependency-spaced order ----
        const int pv = (j + 2) % 3;                 // == (j-1) % 3
        __builtin_amdgcn_s_setprio(1);
#pragma unroll
        for (int u = 0; u < 2; ++u) {
          const char* vb = &vbuf[pv][u][h * 2048 + (ccons + col) * 8];
          long v00 = *(const long*)(vb);             // t16=0, cf=0
          long v01 = *(const long*)(vb + 256);       // t16=0, cf=1
          long v10 = *(const long*)(vb + 4096);      // t16=1, cf=0
          long v11 = *(const long*)(vb + 4096 + 256);
          const char* eb = &ebuf[(j - 1) & 1][u][l * 16];
          u64x2 ev0 = *(const u64x2*)(eb);
          u64x2 ev1 = *(const u64x2*)(eb + 1024);
          // same-acc reuse distance 4
          acc[0][0] = __builtin_amdgcn_mfma_f32_32x32x16_fp8_fp8((long)ev0[0], v00, acc[0][0], 0, 0, 0);
          acc[1][0] = __builtin_amdgcn_mfma_f32_32x32x16_fp8_fp8((long)ev1[0], v00, acc[1][0], 0, 0, 0);
          acc[0][1] = __builtin_amdgcn_mfma_f32_32x32x16_fp8_fp8((long)ev0[0], v01, acc[0][1], 0, 0, 0);
          acc[1][1] = __builtin_amdgcn_mfma_f32_32x32x16_fp8_fp8((long)ev1[0], v01, acc[1][1], 0, 0, 0);
          acc[0][0] = __builtin_amdgcn_mfma_f32_32x32x16_fp8_fp8((long)ev0[1], v10, acc[0][0], 0, 0, 0);
          acc[1][0] = __builtin_amdgcn_mfma_f32_32x32x16_fp8_fp8((long)ev1[1], v10, acc[1][0], 0, 0, 0);
          acc[0][1] = __builtin_amdgcn_mfma_f32_32x32x16_fp8_fp8((long)ev0[1], v11, acc[0][1], 0, 0, 0);
          acc[1][1] = __builtin_amdgcn_mfma_f32_32x32x16_fp8_fp8((long)ev1[1], v11, acc[1][1], 0, 0, 0);
        }
        __builtin_amdgcn_s_setprio(0);
      }
    }

    if (j < J) __syncthreads();
  }

  // ---- consumer epilogue: write bf16 D tiles [m][c]-major ----
  if (!isP) {
    unsigned short* pb = pout + (((size_t)ns * NB + b) * NN + m0) * CC + ccons;
#pragma unroll
    for (int mf = 0; mf < 2; ++mf)
#pragma unroll
      for (int cf = 0; cf < 2; ++cf)
#pragma unroll
        for (int r = 0; r < 16; ++r) {
          int mloc = 32 * mf + (r & 3) + 8 * (r >> 2) + 4 * h;
          pb[(size_t)mloc * CC + 32 * cf + col] = f2bf(acc[mf][cf][r]);
        }
  }
}

// ---------------- Kernel 4: combine + transpose + residual ----------------
__global__ __launch_bounds__(256) void k_comb(
    const unsigned short* __restrict__ pout, const float* __restrict__ x,
    const float* __restrict__ gamma, float* __restrict__ out, int nsplit)
{
  __shared__ float ld[64][65];
  const size_t STRIDE = (size_t)NB * CC * NN;
  const int t = threadIdx.x;
  const int m0 = blockIdx.x * 64, c0 = blockIdx.y * 64, b = blockIdx.z;
  const int ci = t & 63, mo = t >> 6;

  const unsigned short* pb = pout + ((size_t)b * NN + m0) * CC + c0;
#pragma unroll
  for (int rep = 0; rep < 16; ++rep) {
    const int mi = 4 * rep + mo;
    float s = bf2f(pb[(size_t)mi * CC + ci]);
    for (int ns = 1; ns < nsplit; ++ns)
      s += bf2f(pb[ns * STRIDE + (size_t)mi * CC + ci]);
    ld[mi][ci] = s;
  }
  __syncthreads();

  const float g = gamma[0];
  const int mi2 = t & 63;
#pragma unroll
  for (int rep = 0; rep < 16; ++rep) {
    const int cj = 4 * rep + mo;
    const size_t idx = ((size_t)b * CC + c0 + cj) * NN + m0 + mi2;
    out[idx] = g * ld[mi2][cj] + x[idx];
  }
}

// ---------------- launch ---------------------------------------------------
extern "C" void kernel_launch(void* const* d_in, const int* in_sizes, int n_in,
                              void* d_out, int out_size, void* d_ws, size_t ws_size,
                              hipStream_t stream) {
  const float* x     = (const float*)d_in[0];
  const float* Wq    = (const float*)d_in[1];
  const float* bq    = (const float*)d_in[2];
  const float* Wk    = (const float*)d_in[3];
  const float* bk    = (const float*)d_in[4];
  const float* Wv    = (const float*)d_in[5];
  const float* bv    = (const float*)d_in[6];
  const float* gamma = (const float*)d_in[7];
  float* out = (float*)d_out;

  char* ws = (char*)d_ws;
  unsigned short* Qt = (unsigned short*)(ws);                      // 1 MB
  unsigned short* Kt = (unsigned short*)(ws + (1u << 20));         // 1 MB
  unsigned char*  V8 = (unsigned char*)(ws + (2u << 20));          // 4 MB
  unsigned short* Wb = (unsigned short*)(ws + (6u << 20));         // 160 KB
  float* cbias = (float*)(ws + (10u << 20) + (2u << 18));          // 64 KB
  const size_t POUT_OFF = (11u << 20);
  unsigned short* pout = (unsigned short*)(ws + POUT_OFF);
  const size_t PART_BYTES = (size_t)NB * CC * NN * 2;              // 8.4 MB (bf16)

  int nsplit = (ws_size >= POUT_OFF + 2 * PART_BYTES) ? 2 : 1;

  k_wcvt<<<dim3(80), 256, 0, stream>>>(Wq, Wk, Wv, Wb);
  k_proj<<<dim3(NN / 32, NB), 256, 0, stream>>>(x, Wb, bq, bk, bv, Qt, Kt, V8);
  k_rowstats<<<dim3(NN / 32, NB), 256, 0, stream>>>(Qt, Kt, cbias);
  k_attn_out<<<dim3(NB * 64 * nsplit), 384, 0, stream>>>(
      Qt, Kt, V8, cbias, pout, nsplit, NN / nsplit);
  k_comb<<<dim3(NN / 64, CC / 64, NB), 256, 0, stream>>>(pout, x, gamma, out, nsplit);
}

// Round 15
// 97.119 us; speedup vs baseline: 1.3165x; 1.1775x over previous
//
#include <hip/hip_runtime.h>
#include <hip/hip_bf16.h>

// attention_11269994185437: B=4, C=256, CQK=32, H=W=64 -> N=4096
// out = gamma * (V @ P) + x,  P[n,m] = softmax over m of S[n,m], S = Q^T K.
// Qt pre-scaled by L2E: S' = L2E*S. cbias[b][n] = -log2(sum_m exp2(S'[n,m])).
// k_rowstats: S^T = K*Q^T -> reduction axis in-lane, one scalar acc/lane.
// k_attn_out: R11 structure (measured best): 8 waves, m-tile 128, 2-tile
//   intervals, plain __syncthreads; + bf16 partials + dep-spaced MFMA order.
// k_comb: sum bf16 partials, LDS-transpose [m][c]->[c][m], out = g*sum + x.

#define NB 4
#define CC 256
#define NN 4096
#define L2E 1.44269504088896340f

typedef short  short4v  __attribute__((ext_vector_type(4)));
typedef short  short8v  __attribute__((ext_vector_type(8)));
typedef __bf16 bf16x8   __attribute__((ext_vector_type(8)));
typedef float  f32x4    __attribute__((ext_vector_type(4)));
typedef float  f32x16   __attribute__((ext_vector_type(16)));
typedef unsigned long u64x2 __attribute__((ext_vector_type(2)));
typedef unsigned int u32;

#define AS1 __attribute__((address_space(1)))
#define AS3 __attribute__((address_space(3)))

static __device__ __forceinline__ void gload16(const void* g, void* l) {
  __builtin_amdgcn_global_load_lds((const AS1 u32*)g, (AS3 u32*)l, 16, 0, 0);
}

static __device__ __forceinline__ unsigned short f2bf(float f) {
  union { __bf16 h; unsigned short u; } v; v.h = (__bf16)f; return v.u;
}
static __device__ __forceinline__ float bf2f(unsigned short u) {
  union { unsigned u; float f; } v; v.u = (u32)u << 16; return v.f;
}

union FragU { short8v s; bf16x8 b; unsigned u[4]; };

static __device__ __forceinline__ bf16x8 ld_frag(const unsigned short* p) {
  FragU u; u.s = *(const short8v*)p; return u.b;
}

static __device__ __forceinline__ f32x16 zero16() {
  f32x16 v;
#pragma unroll
  for (int i = 0; i < 16; ++i) v[i] = 0.0f;
  return v;
}

static __device__ __forceinline__ f32x16 mfma32(bf16x8 a, bf16x8 b, f32x16 c) {
  return __builtin_amdgcn_mfma_f32_32x32x16_bf16(a, b, c, 0, 0, 0);
}

// ---------------- Kernel 0: W -> bf16 row-major [320][256] ----------------
__global__ __launch_bounds__(256) void k_wcvt(
    const float* __restrict__ Wq, const float* __restrict__ Wk,
    const float* __restrict__ Wv, unsigned short* __restrict__ Wb)
{
  const int i4 = blockIdx.x * 256 + threadIdx.x;     // 80 blocks
  const int e = i4 * 4;
  const int row = e >> 8, c = e & 255;
  const float* src = (row < 32) ? (Wq + row * 256 + c)
                   : (row < 64) ? (Wk + (row - 32) * 256 + c)
                                : (Wv + (row - 64) * 256 + c);
  f32x4 v = *(const f32x4*)src;
  short4v s;
#pragma unroll
  for (int j = 0; j < 4; ++j) s[j] = (short)f2bf(v[j]);
  *(short4v*)(Wb + e) = s;
}

// ---------------- Kernel 1: QKV projection --------------------------------
__global__ __launch_bounds__(256) void k_proj(
    const float* __restrict__ x, const unsigned short* __restrict__ Wb,
    const float* __restrict__ bq, const float* __restrict__ bk,
    const float* __restrict__ bv,
    unsigned short* __restrict__ Qt, unsigned short* __restrict__ Kt,
    unsigned char* __restrict__ V8)
{
  __shared__ unsigned short xs[32][268];   // xs[n_local][c]
  const int t = threadIdx.x;
  const int b = blockIdx.y;
  const int n0 = blockIdx.x * 32;
  const int w = t >> 6, l = t & 63, h = l >> 5, col = l & 31;

  const float* xb = x + (size_t)b * CC * NN;
  {
    const int c_off = t >> 3, nl = 4 * (t & 7);
#pragma unroll
    for (int c0 = 0; c0 < CC; c0 += 32) {
      int c = c0 + c_off;
      f32x4 v4 = *(const f32x4*)(xb + (size_t)c * NN + n0 + nl);
#pragma unroll
      for (int j = 0; j < 4; ++j) xs[nl + j][c] = f2bf(v4[j]);
    }
  }
  __syncthreads();

  for (int f = w; f < 10; f += 4) {
    const float* bsrc; int rowbase; int mode; int wrow;
    if (f == 0)      { bsrc = bq; rowbase = 0;            mode = 0; wrow = 0; }
    else if (f == 1) { bsrc = bk; rowbase = 0;            mode = 1; wrow = 32; }
    else             { bsrc = bv; rowbase = (f - 2) * 32; mode = 2; wrow = 64 + rowbase; }

    f32x16 acc0 = zero16();
    const unsigned short* wr = Wb + (size_t)(wrow + col) * 256 + 8 * h;

#pragma unroll
    for (int k0 = 0; k0 < CC; k0 += 16) {
      FragU a;
      a.s = *(const short8v*)(wr + k0);
      const unsigned short* p0 = &xs[col][k0 + 8 * h];
      FragU b0;
      short4v t0a = *(const short4v*)p0, t0b = *(const short4v*)(p0 + 4);
#pragma unroll
      for (int j = 0; j < 4; ++j) { b0.s[j] = t0a[j]; b0.s[4 + j] = t0b[j]; }
      acc0 = mfma32(a.b, b0.b, acc0);
    }

    const int n = n0 + col;
#pragma unroll
    for (int q = 0; q < 4; ++q) {
      f32x4 bias4 = *(const f32x4*)(bsrc + rowbase + 8 * q + 4 * h);
      float vals[4];
#pragma unroll
      for (int i = 0; i < 4; ++i) vals[i] = acc0[4 * q + i] + bias4[i];
      if (mode == 2) {
        // V8[b][n>>4][(n&15)>>3][c][n&7]
        const size_t tb = (((size_t)b * (NN >> 4) + (n >> 4)) * 2 + ((n >> 3) & 1)) * CC * 8
                          + (n & 7);
        u32 w01 = __builtin_amdgcn_cvt_pk_fp8_f32(vals[0], vals[1], 0, false);
        u32 w23 = __builtin_amdgcn_cvt_pk_fp8_f32(vals[2], vals[3], 0, false);
        const int cb0 = rowbase + 8 * q + 4 * h;
        V8[tb + (size_t)(cb0 + 0) * 8] = (unsigned char)(w01 & 0xff);
        V8[tb + (size_t)(cb0 + 1) * 8] = (unsigned char)((w01 >> 8) & 0xff);
        V8[tb + (size_t)(cb0 + 2) * 8] = (unsigned char)(w23 & 0xff);
        V8[tb + (size_t)(cb0 + 3) * 8] = (unsigned char)((w23 >> 8) & 0xff);
      } else {
        unsigned short* dst = (mode == 0) ? Qt : Kt;
        const float scale = (mode == 0) ? L2E : 1.0f;   // fold L2E into Q
        short4v s4;
#pragma unroll
        for (int i = 0; i < 4; ++i) s4[i] = (short)f2bf(vals[i] * scale);
        *(short4v*)(dst + ((size_t)b * NN + n) * 32 + 8 * q + 4 * h) = s4;
      }
    }
  }
}

// ---------------- Kernel 2: row sums -> cbias (transposed MFMA) -----------
__global__ __launch_bounds__(256) void k_rowstats(
    const unsigned short* __restrict__ Qt, const unsigned short* __restrict__ Kt,
    float* __restrict__ cbias)
{
  __shared__ float ssum[4][32];
  const int t = threadIdx.x;
  const int w = t >> 6, l = t & 63, h = l >> 5, col = l & 31;
  const int b = blockIdx.y;
  const int n0 = blockIdx.x * 32;
  const unsigned short* Qb = Qt + (size_t)b * NN * 32;
  const unsigned short* Kb = Kt + (size_t)b * NN * 32;

  bf16x8 bq0 = ld_frag(Qb + (size_t)(n0 + col) * 32 + 8 * h);
  bf16x8 bq1 = ld_frag(Qb + (size_t)(n0 + col) * 32 + 16 + 8 * h);

  float acc = 0.0f;
  const int mbase = w * (NN / 4);
#pragma unroll 2
  for (int mt = 0; mt < 32; ++mt) {
    const int m0 = mbase + mt * 32;
    bf16x8 ak0 = ld_frag(Kb + (size_t)(m0 + col) * 32 + 8 * h);
    bf16x8 ak1 = ld_frag(Kb + (size_t)(m0 + col) * 32 + 16 + 8 * h);
    f32x16 S = zero16();
    S = mfma32(ak0, bq0, S);
    S = mfma32(ak1, bq1, S);
    float p0 = 0.0f, p1 = 0.0f, p2 = 0.0f, p3 = 0.0f;
#pragma unroll
    for (int r = 0; r < 4; ++r) {
      p0 += __builtin_amdgcn_exp2f(S[r]);
      p1 += __builtin_amdgcn_exp2f(S[4 + r]);
      p2 += __builtin_amdgcn_exp2f(S[8 + r]);
      p3 += __builtin_amdgcn_exp2f(S[12 + r]);
    }
    acc += (p0 + p1) + (p2 + p3);
  }
  acc += __shfl_xor(acc, 32);

  if (l < 32) ssum[w][l] = acc;
  __syncthreads();

  if (t < 32) {
    float s = (ssum[0][t] + ssum[1][t]) + (ssum[2][t] + ssum[3][t]);
    cbias[(size_t)b * NN + n0 + t] = -__builtin_amdgcn_logf(s);
  }
}

// ---------------- Kernel 3: out^T = E^T * V^T, prod/cons, 2-tile interval -
// grid 128*nsplit (XCD-swizzled), 8 waves (512 thr). m-tile 128, all 256 c.
// waves 0-3: producer for m-frag w.  waves 4-7: consumer for c-quarter w-4.
// Interval j = tiles {2j, 2j+1}. One __syncthreads per interval.
__global__ __launch_bounds__(512) void k_attn_out(
    const unsigned short* __restrict__ Qt, const unsigned short* __restrict__ Kt,
    const unsigned char* __restrict__ V8,
    const float* __restrict__ cbias,
    unsigned short* __restrict__ pout,
    int nsplit, int nlen)
{
  __shared__ __align__(16) char qbuf[2][2][2048];  // [buf][u] Q frag-linear
  __shared__ __align__(16) char vbuf[3][2][8192];  // [buf][u] V [t16][kh][c][8]
  __shared__ __align__(16) char ebuf[2][2][4096];  // [buf][u] E A-frags [mf][lane][16B]

  const int wg = (int)blockIdx.x;
  const int chunk = (int)gridDim.x >> 3;           // blocks per XCD (bijective)
  const int id2 = (wg & 7) * chunk + (wg >> 3);
  const int per_b = 32 * nsplit;                   // m-tiles(128) per batch * nsplit
  const int b = id2 / per_b;
  const int rem = id2 - b * per_b;
  const int ns = rem >> 5;
  const int m0 = (rem & 31) * 128;
  const int nbeg = ns * nlen;

  const int t = threadIdx.x;
  const int w = t >> 6, l = t & 63, h = l >> 5, col = l & 31;
  const int mfp = w & 3;                           // producer m-frag
  const int ccons = (w & 3) * 64;                  // consumer c-quarter

  const unsigned short* Kb = Kt + (size_t)b * NN * 32;
  const float* cb = cbias + (size_t)b * NN + nbeg;

  // producer K fragments (B operand of S), loop-invariant
  bf16x8 bk0 = ld_frag(Kb + (size_t)(m0 + 32 * mfp + col) * 32 + 8 * h);
  bf16x8 bk1 = ld_frag(Kb + (size_t)(m0 + 32 * mfp + col) * 32 + 16 + 8 * h);

  // Q staging: per tile 128 chunks of 16B; all 8 waves, lanes 0-15.
  const int ll = l & 15;
  const size_t gqoff = (size_t)(((w & 1) * 16 + ll) * 64 + ((w >> 1) & 1) * 16
                                + (w >> 2) * 32);
  const char* qsrc = (const char*)Qt + ((size_t)b * NN + nbeg) * 64 + gqoff;
  const char* vsrc = (const char*)V8 + ((size_t)b * (NN >> 4) + (nbeg >> 4)) * 4096
                     + (size_t)t * 16;

  f32x16 acc[4][2];
#pragma unroll
  for (int mf = 0; mf < 4; ++mf)
#pragma unroll
    for (int cf = 0; cf < 2; ++cf) acc[mf][cf] = zero16();

  const int J = nlen >> 6;                          // intervals of 64 n

  // ---- prologue: stage interval 0 (tiles 0,1) ----
  if (ll == l) {                                    // lanes 0-15
    gload16(qsrc, &qbuf[0][0][w * 256]);
    gload16(qsrc + 2048, &qbuf[0][1][w * 256]);
  }
  gload16(vsrc, &vbuf[0][0][w * 1024]);
  gload16(vsrc + 8192, &vbuf[0][1][w * 1024]);
  __syncthreads();

  for (int j = 0; j <= J; ++j) {
    // ---- stage interval j+1 (tiles 2j+2, 2j+3) ----
    if (j + 1 < J) {
      const size_t qoff = (size_t)(2 * j + 2) * 2048;
      const size_t voff = (size_t)(2 * j + 2) * 8192;
      const int qs = (j + 1) & 1, vs = (j + 1) % 3;
      if (ll == l) {
        gload16(qsrc + qoff, &qbuf[qs][0][w * 256]);
        gload16(qsrc + qoff + 2048, &qbuf[qs][1][w * 256]);
      }
      gload16(vsrc + voff, &vbuf[vs][0][w * 1024]);
      gload16(vsrc + voff + 8192, &vbuf[vs][1][w * 1024]);
    }

    if (w < 4) {
      if (j < J) {
        // ---- producer: two independent S->E chains (tiles 2j, 2j+1) ----
#pragma unroll
        for (int u = 0; u < 2; ++u) {
          const char* qb = &qbuf[j & 1][u][0];
          FragU fq0, fq1;
          fq0.s = *(const short8v*)(qb + l * 16);
          fq1.s = *(const short8v*)(qb + 1024 + l * 16);
          f32x16 S = zero16();
          S = mfma32(fq0.b, bk0, S);
          S = mfma32(fq1.b, bk1, S);

          float e[16];
          const float* cbi = cb + (2 * j + u) * 32;
#pragma unroll
          for (int q = 0; q < 4; ++q) {
            f32x4 cb4 = *(const f32x4*)(cbi + 8 * q + 4 * h);
#pragma unroll
            for (int i = 0; i < 4; ++i)
              e[4 * q + i] = __builtin_amdgcn_exp2f(S[4 * q + i] + cb4[i]);
          }
          u32 wA = __builtin_amdgcn_cvt_pk_fp8_f32(e[0], e[1], 0, false);
          wA = __builtin_amdgcn_cvt_pk_fp8_f32(e[2], e[3], wA, true);
          u32 wB = __builtin_amdgcn_cvt_pk_fp8_f32(e[4], e[5], 0, false);
          wB = __builtin_amdgcn_cvt_pk_fp8_f32(e[6], e[7], wB, true);
          u32 wC = __builtin_amdgcn_cvt_pk_fp8_f32(e[8], e[9], 0, false);
          wC = __builtin_amdgcn_cvt_pk_fp8_f32(e[10], e[11], wC, true);
          u32 wD = __builtin_amdgcn_cvt_pk_fp8_f32(e[12], e[13], 0, false);
          wD = __builtin_amdgcn_cvt_pk_fp8_f32(e[14], e[15], wD, true);
          asm("v_permlane32_swap_b32 %0, %1" : "+v"(wA), "+v"(wB));
          asm("v_permlane32_swap_b32 %0, %1" : "+v"(wC), "+v"(wD));
          u64x2 ev;
          ev[0] = ((unsigned long)wB << 32) | wA;   // A0: n' 0..15
          ev[1] = ((unsigned long)wD << 32) | wC;   // A1: n' 16..31
          *(u64x2*)(&ebuf[j & 1][u][mfp * 1024 + l * 16]) = ev;
        }
      }
    } else {
      if (j > 0) {
        // ---- consumer: PV for interval j-1, dependency-spaced order ----
        const int pv = (j + 2) % 3;                 // == (j-1) % 3
        __builtin_amdgcn_s_setprio(1);
#pragma unroll
        for (int u = 0; u < 2; ++u) {
          const char* vb = &vbuf[pv][u][h * 2048 + (ccons + col) * 8];
          long v00 = *(const long*)(vb);             // t16=0, cf=0
          long v01 = *(const long*)(vb + 256);       // t16=0, cf=1
          long v10 = *(const long*)(vb + 4096);      // t16=1, cf=0
          long v11 = *(const long*)(vb + 4096 + 256);
          const char* eb = &ebuf[(j - 1) & 1][u][l * 16];
          u64x2 ev0 = *(const u64x2*)(eb);
          u64x2 ev1 = *(const u64x2*)(eb + 1024);
          u64x2 ev2 = *(const u64x2*)(eb + 2048);
          u64x2 ev3 = *(const u64x2*)(eb + 3072);
          // same-acc reuse distance 8
          acc[0][0] = __builtin_amdgcn_mfma_f32_32x32x16_fp8_fp8((long)ev0[0], v00, acc[0][0], 0, 0, 0);
          acc[1][0] = __builtin_amdgcn_mfma_f32_32x32x16_fp8_fp8((long)ev1[0], v00, acc[1][0], 0, 0, 0);
          acc[2][0] = __builtin_amdgcn_mfma_f32_32x32x16_fp8_fp8((long)ev2[0], v00, acc[2][0], 0, 0, 0);
          acc[3][0] = __builtin_amdgcn_mfma_f32_32x32x16_fp8_fp8((long)ev3[0], v00, acc[3][0], 0, 0, 0);
          acc[0][1] = __builtin_amdgcn_mfma_f32_32x32x16_fp8_fp8((long)ev0[0], v01, acc[0][1], 0, 0, 0);
          acc[1][1] = __builtin_amdgcn_mfma_f32_32x32x16_fp8_fp8((long)ev1[0], v01, acc[1][1], 0, 0, 0);
          acc[2][1] = __builtin_amdgcn_mfma_f32_32x32x16_fp8_fp8((long)ev2[0], v01, acc[2][1], 0, 0, 0);
          acc[3][1] = __builtin_amdgcn_mfma_f32_32x32x16_fp8_fp8((long)ev3[0], v01, acc[3][1], 0, 0, 0);
          acc[0][0] = __builtin_amdgcn_mfma_f32_32x32x16_fp8_fp8((long)ev0[1], v10, acc[0][0], 0, 0, 0);
          acc[1][0] = __builtin_amdgcn_mfma_f32_32x32x16_fp8_fp8((long)ev1[1], v10, acc[1][0], 0, 0, 0);
          acc[2][0] = __builtin_amdgcn_mfma_f32_32x32x16_fp8_fp8((long)ev2[1], v10, acc[2][0], 0, 0, 0);
          acc[3][0] = __builtin_amdgcn_mfma_f32_32x32x16_fp8_fp8((long)ev3[1], v10, acc[3][0], 0, 0, 0);
          acc[0][1] = __builtin_amdgcn_mfma_f32_32x32x16_fp8_fp8((long)ev0[1], v11, acc[0][1], 0, 0, 0);
          acc[1][1] = __builtin_amdgcn_mfma_f32_32x32x16_fp8_fp8((long)ev1[1], v11, acc[1][1], 0, 0, 0);
          acc[2][1] = __builtin_amdgcn_mfma_f32_32x32x16_fp8_fp8((long)ev2[1], v11, acc[2][1], 0, 0, 0);
          acc[3][1] = __builtin_amdgcn_mfma_f32_32x32x16_fp8_fp8((long)ev3[1], v11, acc[3][1], 0, 0, 0);
        }
        __builtin_amdgcn_s_setprio(0);
      }
    }

    if (j < J) __syncthreads();
  }

  // ---- consumer epilogue: write bf16 D tiles [m][c]-major ----
  if (w >= 4) {
    unsigned short* pb = pout + (((size_t)ns * NB + b) * NN + m0) * CC + ccons;
#pragma unroll
    for (int mf = 0; mf < 4; ++mf)
#pragma unroll
      for (int cf = 0; cf < 2; ++cf)
#pragma unroll
        for (int r = 0; r < 16; ++r) {
          int mloc = 32 * mf + (r & 3) + 8 * (r >> 2) + 4 * h;
          pb[(size_t)mloc * CC + 32 * cf + col] = f2bf(acc[mf][cf][r]);
        }
  }
}

// ---------------- Kernel 4: combine + transpose + residual ----------------
__global__ __launch_bounds__(256) void k_comb(
    const unsigned short* __restrict__ pout, const float* __restrict__ x,
    const float* __restrict__ gamma, float* __restrict__ out, int nsplit)
{
  __shared__ float ld[64][65];
  const size_t STRIDE = (size_t)NB * CC * NN;
  const int t = threadIdx.x;
  const int m0 = blockIdx.x * 64, c0 = blockIdx.y * 64, b = blockIdx.z;
  const int ci = t & 63, mo = t >> 6;

  const unsigned short* pb = pout + ((size_t)b * NN + m0) * CC + c0;
#pragma unroll
  for (int rep = 0; rep < 16; ++rep) {
    const int mi = 4 * rep + mo;
    float s = bf2f(pb[(size_t)mi * CC + ci]);
    for (int ns = 1; ns < nsplit; ++ns)
      s += bf2f(pb[ns * STRIDE + (size_t)mi * CC + ci]);
    ld[mi][ci] = s;
  }
  __syncthreads();

  const float g = gamma[0];
  const int mi2 = t & 63;
#pragma unroll
  for (int rep = 0; rep < 16; ++rep) {
    const int cj = 4 * rep + mo;
    const size_t idx = ((size_t)b * CC + c0 + cj) * NN + m0 + mi2;
    out[idx] = g * ld[mi2][cj] + x[idx];
  }
}

// ---------------- launch ---------------------------------------------------
extern "C" void kernel_launch(void* const* d_in, const int* in_sizes, int n_in,
                              void* d_out, int out_size, void* d_ws, size_t ws_size,
                              hipStream_t stream) {
  const float* x     = (const float*)d_in[0];
  const float* Wq    = (const float*)d_in[1];
  const float* bq    = (const float*)d_in[2];
  const float* Wk    = (const float*)d_in[3];
  const float* bk    = (const float*)d_in[4];
  const float* Wv    = (const float*)d_in[5];
  const float* bv    = (const float*)d_in[6];
  const float* gamma = (const float*)d_in[7];
  float* out = (float*)d_out;

  char* ws = (char*)d_ws;
  unsigned short* Qt = (unsigned short*)(ws);                      // 1 MB
  unsigned short* Kt = (unsigned short*)(ws + (1u << 20));         // 1 MB
  unsigned char*  V8 = (unsigned char*)(ws + (2u << 20));          // 4 MB
  unsigned short* Wb = (unsigned short*)(ws + (6u << 20));         // 160 KB
  float* cbias = (float*)(ws + (10u << 20) + (2u << 18));          // 64 KB
  const size_t POUT_OFF = (11u << 20);
  unsigned short* pout = (unsigned short*)(ws + POUT_OFF);
  const size_t PART_BYTES = (size_t)NB * CC * NN * 2;              // 8.4 MB (bf16)

  int nsplit = (ws_size >= POUT_OFF + 2 * PART_BYTES) ? 2 : 1;

  k_wcvt<<<dim3(80), 256, 0, stream>>>(Wq, Wk, Wv, Wb);
  k_proj<<<dim3(NN / 32, NB), 256, 0, stream>>>(x, Wb, bq, bk, bv, Qt, Kt, V8);
  k_rowstats<<<dim3(NN / 32, NB), 256, 0, stream>>>(Qt, Kt, cbias);
  k_attn_out<<<dim3(128 * nsplit), 512, 0, stream>>>(
      Qt, Kt, V8, cbias, pout, nsplit, NN / nsplit);
  k_comb<<<dim3(NN / 64, CC / 64, NB), 256, 0, stream>>>(pout, x, gamma, out, nsplit);
}

// Round 16
// 94.418 us; speedup vs baseline: 1.3541x; 1.0286x over previous
//
#include <hip/hip_runtime.h>
#include <hip/hip_bf16.h>

// attention_11269994185437: B=4, C=256, CQK=32, H=W=64 -> N=4096
// out = gamma * (V @ P) + x,  P[n,m] = softmax over m of S[n,m], S = Q^T K.
// Qt pre-scaled by L2E: S' = L2E*S. cbias[b][n] = -log2(sum_m exp2(S'[n,m])).
// k_rowstats: S^T = K*Q^T, 8 waves, n-tile 64, K-frag reuse x2.
// k_attn_out: R15 structure, but V goes DIRECT TO REGISTERS (double-buffered
//   dwordx4, layout V8[b][nt32][kh][c][t16*8+j]) -- no vbuf LDS round trip.
// k_comb: sum bf16 partials, LDS-transpose [m][c]->[c][m], out = g*sum + x.

#define NB 4
#define CC 256
#define NN 4096
#define L2E 1.44269504088896340f

typedef short  short4v  __attribute__((ext_vector_type(4)));
typedef short  short8v  __attribute__((ext_vector_type(8)));
typedef __bf16 bf16x8   __attribute__((ext_vector_type(8)));
typedef float  f32x4    __attribute__((ext_vector_type(4)));
typedef float  f32x16   __attribute__((ext_vector_type(16)));
typedef unsigned long u64x2 __attribute__((ext_vector_type(2)));
typedef unsigned int u32;

#define AS1 __attribute__((address_space(1)))
#define AS3 __attribute__((address_space(3)))

static __device__ __forceinline__ void gload16(const void* g, void* l) {
  __builtin_amdgcn_global_load_lds((const AS1 u32*)g, (AS3 u32*)l, 16, 0, 0);
}

static __device__ __forceinline__ unsigned short f2bf(float f) {
  union { __bf16 h; unsigned short u; } v; v.h = (__bf16)f; return v.u;
}
static __device__ __forceinline__ float bf2f(unsigned short u) {
  union { unsigned u; float f; } v; v.u = (u32)u << 16; return v.f;
}

union FragU { short8v s; bf16x8 b; unsigned u[4]; };

static __device__ __forceinline__ bf16x8 ld_frag(const unsigned short* p) {
  FragU u; u.s = *(const short8v*)p; return u.b;
}

static __device__ __forceinline__ f32x16 zero16() {
  f32x16 v;
#pragma unroll
  for (int i = 0; i < 16; ++i) v[i] = 0.0f;
  return v;
}

static __device__ __forceinline__ f32x16 mfma32(bf16x8 a, bf16x8 b, f32x16 c) {
  return __builtin_amdgcn_mfma_f32_32x32x16_bf16(a, b, c, 0, 0, 0);
}

// ---------------- Kernel 0: W -> bf16 row-major [320][256] ----------------
__global__ __launch_bounds__(256) void k_wcvt(
    const float* __restrict__ Wq, const float* __restrict__ Wk,
    const float* __restrict__ Wv, unsigned short* __restrict__ Wb)
{
  const int i4 = blockIdx.x * 256 + threadIdx.x;     // 80 blocks
  const int e = i4 * 4;
  const int row = e >> 8, c = e & 255;
  const float* src = (row < 32) ? (Wq + row * 256 + c)
                   : (row < 64) ? (Wk + (row - 32) * 256 + c)
                                : (Wv + (row - 64) * 256 + c);
  f32x4 v = *(const f32x4*)src;
  short4v s;
#pragma unroll
  for (int j = 0; j < 4; ++j) s[j] = (short)f2bf(v[j]);
  *(short4v*)(Wb + e) = s;
}

// ---------------- Kernel 1: QKV projection --------------------------------
// Qt[b][n][32] bf16 (L2E-scaled), Kt[b][n][32] bf16,
// V8[b][n>>5][(n>>3)&1][c][((n>>4)&1)*8 + (n&7)] fp8 e4m3.
__global__ __launch_bounds__(256) void k_proj(
    const float* __restrict__ x, const unsigned short* __restrict__ Wb,
    const float* __restrict__ bq, const float* __restrict__ bk,
    const float* __restrict__ bv,
    unsigned short* __restrict__ Qt, unsigned short* __restrict__ Kt,
    unsigned char* __restrict__ V8)
{
  __shared__ unsigned short xs[32][268];   // xs[n_local][c]
  const int t = threadIdx.x;
  const int b = blockIdx.y;
  const int n0 = blockIdx.x * 32;
  const int w = t >> 6, l = t & 63, h = l >> 5, col = l & 31;

  const float* xb = x + (size_t)b * CC * NN;
  {
    const int c_off = t >> 3, nl = 4 * (t & 7);
#pragma unroll
    for (int c0 = 0; c0 < CC; c0 += 32) {
      int c = c0 + c_off;
      f32x4 v4 = *(const f32x4*)(xb + (size_t)c * NN + n0 + nl);
#pragma unroll
      for (int j = 0; j < 4; ++j) xs[nl + j][c] = f2bf(v4[j]);
    }
  }
  __syncthreads();

  for (int f = w; f < 10; f += 4) {
    const float* bsrc; int rowbase; int mode; int wrow;
    if (f == 0)      { bsrc = bq; rowbase = 0;            mode = 0; wrow = 0; }
    else if (f == 1) { bsrc = bk; rowbase = 0;            mode = 1; wrow = 32; }
    else             { bsrc = bv; rowbase = (f - 2) * 32; mode = 2; wrow = 64 + rowbase; }

    f32x16 acc0 = zero16();
    const unsigned short* wr = Wb + (size_t)(wrow + col) * 256 + 8 * h;

#pragma unroll
    for (int k0 = 0; k0 < CC; k0 += 16) {
      FragU a;
      a.s = *(const short8v*)(wr + k0);
      const unsigned short* p0 = &xs[col][k0 + 8 * h];
      FragU b0;
      short4v t0a = *(const short4v*)p0, t0b = *(const short4v*)(p0 + 4);
#pragma unroll
      for (int j = 0; j < 4; ++j) { b0.s[j] = t0a[j]; b0.s[4 + j] = t0b[j]; }
      acc0 = mfma32(a.b, b0.b, acc0);
    }

    const int n = n0 + col;
#pragma unroll
    for (int q = 0; q < 4; ++q) {
      f32x4 bias4 = *(const f32x4*)(bsrc + rowbase + 8 * q + 4 * h);
      float vals[4];
#pragma unroll
      for (int i = 0; i < 4; ++i) vals[i] = acc0[4 * q + i] + bias4[i];
      if (mode == 2) {
        // V8 byte = (((b*128 + n>>5)*2 + kh)*256 + c)*16 + t16*8 + (n&7)
        const size_t tb = ((((size_t)b * 128 + (n >> 5)) * 2 + ((n >> 3) & 1)) * 256) * 16
                          + ((n >> 4) & 1) * 8 + (n & 7);
        u32 w01 = __builtin_amdgcn_cvt_pk_fp8_f32(vals[0], vals[1], 0, false);
        u32 w23 = __builtin_amdgcn_cvt_pk_fp8_f32(vals[2], vals[3], 0, false);
        const int cb0 = rowbase + 8 * q + 4 * h;
        V8[tb + (size_t)(cb0 + 0) * 16] = (unsigned char)(w01 & 0xff);
        V8[tb + (size_t)(cb0 + 1) * 16] = (unsigned char)((w01 >> 8) & 0xff);
        V8[tb + (size_t)(cb0 + 2) * 16] = (unsigned char)(w23 & 0xff);
        V8[tb + (size_t)(cb0 + 3) * 16] = (unsigned char)((w23 >> 8) & 0xff);
      } else {
        unsigned short* dst = (mode == 0) ? Qt : Kt;
        const float scale = (mode == 0) ? L2E : 1.0f;   // fold L2E into Q
        short4v s4;
#pragma unroll
        for (int i = 0; i < 4; ++i) s4[i] = (short)f2bf(vals[i] * scale);
        *(short4v*)(dst + ((size_t)b * NN + n) * 32 + 8 * q + 4 * h) = s4;
      }
    }
  }
}

// ---------------- Kernel 2: row sums -> cbias (transposed MFMA) -----------
// grid (N/64, B), block 512 (8 waves). Wave w sweeps m in [w*512,(w+1)*512),
// handles 2 n-frags (K-frags reused). In-lane sum, shfl_xor(32), LDS merge.
__global__ __launch_bounds__(512) void k_rowstats(
    const unsigned short* __restrict__ Qt, const unsigned short* __restrict__ Kt,
    float* __restrict__ cbias)
{
  __shared__ float ssum[8][64];
  const int t = threadIdx.x;
  const int w = t >> 6, l = t & 63, h = l >> 5, col = l & 31;
  const int b = blockIdx.y;
  const int n0 = blockIdx.x * 64;
  const unsigned short* Qb = Qt + (size_t)b * NN * 32;
  const unsigned short* Kb = Kt + (size_t)b * NN * 32;

  bf16x8 bq00 = ld_frag(Qb + (size_t)(n0 + col) * 32 + 8 * h);
  bf16x8 bq01 = ld_frag(Qb + (size_t)(n0 + col) * 32 + 16 + 8 * h);
  bf16x8 bq10 = ld_frag(Qb + (size_t)(n0 + 32 + col) * 32 + 8 * h);
  bf16x8 bq11 = ld_frag(Qb + (size_t)(n0 + 32 + col) * 32 + 16 + 8 * h);

  float acc0 = 0.0f, acc1 = 0.0f;
  const int mbase = w * (NN / 8);
#pragma unroll 2
  for (int mt = 0; mt < 16; ++mt) {
    const int m0 = mbase + mt * 32;
    bf16x8 ak0 = ld_frag(Kb + (size_t)(m0 + col) * 32 + 8 * h);
    bf16x8 ak1 = ld_frag(Kb + (size_t)(m0 + col) * 32 + 16 + 8 * h);
    f32x16 S0 = zero16(), S1 = zero16();
    S0 = mfma32(ak0, bq00, S0);
    S0 = mfma32(ak1, bq01, S0);
    S1 = mfma32(ak0, bq10, S1);
    S1 = mfma32(ak1, bq11, S1);
    float p0 = 0.0f, p1 = 0.0f, p2 = 0.0f, p3 = 0.0f;
#pragma unroll
    for (int r = 0; r < 8; ++r) {
      p0 += __builtin_amdgcn_exp2f(S0[r]);
      p1 += __builtin_amdgcn_exp2f(S0[8 + r]);
      p2 += __builtin_amdgcn_exp2f(S1[r]);
      p3 += __builtin_amdgcn_exp2f(S1[8 + r]);
    }
    acc0 += p0 + p1;
    acc1 += p2 + p3;
  }
  acc0 += __shfl_xor(acc0, 32);
  acc1 += __shfl_xor(acc1, 32);

  if (l < 32) { ssum[w][l] = acc0; ssum[w][32 + l] = acc1; }
  __syncthreads();

  if (t < 64) {
    float s = 0.0f;
#pragma unroll
    for (int wv = 0; wv < 8; ++wv) s += ssum[wv][t];
    cbias[(size_t)b * NN + n0 + t] = -__builtin_amdgcn_logf(s);
  }
}

// ---------------- Kernel 3: out^T = E^T * V^T, V direct-to-register -------
// grid 128*nsplit (XCD-swizzled), 8 waves (512 thr). m-tile 128, all 256 c.
// waves 0-3: producer m-frag w.  waves 4-7: consumer c-quarter (w-4)*64.
// Interval j = tiles {2j, 2j+1}; one __syncthreads per interval.
// Consumer V: dwordx4 pairs double-buffered in registers (no LDS).
#define V_ISSUE(SET, TJ)                                                       \
  {                                                                            \
    const char* vg_ = vg + (size_t)(TJ) * 8192;                                \
    SET##A0 = *(const u64x2*)(vg_);                                            \
    SET##B0 = *(const u64x2*)(vg_ + 512);                                      \
    SET##A1 = *(const u64x2*)(vg_ + 8192);                                     \
    SET##B1 = *(const u64x2*)(vg_ + 8192 + 512);                               \
  }

#define PV_U(EBP, vA, vB)                                                      \
  {                                                                            \
    const char* eb_ = (EBP);                                                   \
    u64x2 ev0 = *(const u64x2*)(eb_);                                          \
    u64x2 ev1 = *(const u64x2*)(eb_ + 1024);                                   \
    u64x2 ev2 = *(const u64x2*)(eb_ + 2048);                                   \
    u64x2 ev3 = *(const u64x2*)(eb_ + 3072);                                   \
    long v00 = (long)vA[0], v10 = (long)vA[1];                                 \
    long v01 = (long)vB[0], v11 = (long)vB[1];                                 \
    acc[0][0] = __builtin_amdgcn_mfma_f32_32x32x16_fp8_fp8((long)ev0[0], v00, acc[0][0], 0, 0, 0); \
    acc[1][0] = __builtin_amdgcn_mfma_f32_32x32x16_fp8_fp8((long)ev1[0], v00, acc[1][0], 0, 0, 0); \
    acc[2][0] = __builtin_amdgcn_mfma_f32_32x32x16_fp8_fp8((long)ev2[0], v00, acc[2][0], 0, 0, 0); \
    acc[3][0] = __builtin_amdgcn_mfma_f32_32x32x16_fp8_fp8((long)ev3[0], v00, acc[3][0], 0, 0, 0); \
    acc[0][1] = __builtin_amdgcn_mfma_f32_32x32x16_fp8_fp8((long)ev0[0], v01, acc[0][1], 0, 0, 0); \
    acc[1][1] = __builtin_amdgcn_mfma_f32_32x32x16_fp8_fp8((long)ev1[0], v01, acc[1][1], 0, 0, 0); \
    acc[2][1] = __builtin_amdgcn_mfma_f32_32x32x16_fp8_fp8((long)ev2[0], v01, acc[2][1], 0, 0, 0); \
    acc[3][1] = __builtin_amdgcn_mfma_f32_32x32x16_fp8_fp8((long)ev3[0], v01, acc[3][1], 0, 0, 0); \
    acc[0][0] = __builtin_amdgcn_mfma_f32_32x32x16_fp8_fp8((long)ev0[1], v10, acc[0][0], 0, 0, 0); \
    acc[1][0] = __builtin_amdgcn_mfma_f32_32x32x16_fp8_fp8((long)ev1[1], v10, acc[1][0], 0, 0, 0); \
    acc[2][0] = __builtin_amdgcn_mfma_f32_32x32x16_fp8_fp8((long)ev2[1], v10, acc[2][0], 0, 0, 0); \
    acc[3][0] = __builtin_amdgcn_mfma_f32_32x32x16_fp8_fp8((long)ev3[1], v10, acc[3][0], 0, 0, 0); \
    acc[0][1] = __builtin_amdgcn_mfma_f32_32x32x16_fp8_fp8((long)ev0[1], v11, acc[0][1], 0, 0, 0); \
    acc[1][1] = __builtin_amdgcn_mfma_f32_32x32x16_fp8_fp8((long)ev1[1], v11, acc[1][1], 0, 0, 0); \
    acc[2][1] = __builtin_amdgcn_mfma_f32_32x32x16_fp8_fp8((long)ev2[1], v11, acc[2][1], 0, 0, 0); \
    acc[3][1] = __builtin_amdgcn_mfma_f32_32x32x16_fp8_fp8((long)ev3[1], v11, acc[3][1], 0, 0, 0); \
  }

#define K3_ITER(J, CUR, NXT)                                                   \
  if ((J) <= KJ) {                                                             \
    const int j_ = (J);                                                        \
    if (j_ + 1 < KJ) {                                                         \
      const size_t qoff_ = (size_t)(2 * j_ + 2) * 2048;                        \
      const int qs_ = (j_ + 1) & 1;                                            \
      if (ll == l) {                                                           \
        gload16(qsrc + qoff_, &qbuf[qs_][0][w * 256]);                         \
        gload16(qsrc + qoff_ + 2048, &qbuf[qs_][1][w * 256]);                  \
      }                                                                        \
    }                                                                          \
    if (w < 4) {                                                               \
      if (j_ < KJ) {                                                           \
        _Pragma("unroll")                                                      \
        for (int u = 0; u < 2; ++u) {                                          \
          const char* qb = &qbuf[j_ & 1][u][0];                                \
          FragU fq0, fq1;                                                      \
          fq0.s = *(const short8v*)(qb + l * 16);                              \
          fq1.s = *(const short8v*)(qb + 1024 + l * 16);                       \
          f32x16 S = zero16();                                                 \
          S = mfma32(fq0.b, bk0, S);                                           \
          S = mfma32(fq1.b, bk1, S);                                           \
          float e[16];                                                         \
          const float* cbi = cb + (2 * j_ + u) * 32;                           \
          _Pragma("unroll")                                                    \
          for (int q = 0; q < 4; ++q) {                                        \
            f32x4 cb4 = *(const f32x4*)(cbi + 8 * q + 4 * h);                  \
            _Pragma("unroll")                                                  \
            for (int i = 0; i < 4; ++i)                                        \
              e[4 * q + i] = __builtin_amdgcn_exp2f(S[4 * q + i] + cb4[i]);    \
          }                                                                    \
          u32 wA = __builtin_amdgcn_cvt_pk_fp8_f32(e[0], e[1], 0, false);      \
          wA = __builtin_amdgcn_cvt_pk_fp8_f32(e[2], e[3], wA, true);          \
          u32 wB = __builtin_amdgcn_cvt_pk_fp8_f32(e[4], e[5], 0, false);      \
          wB = __builtin_amdgcn_cvt_pk_fp8_f32(e[6], e[7], wB, true);          \
          u32 wC = __builtin_amdgcn_cvt_pk_fp8_f32(e[8], e[9], 0, false);      \
          wC = __builtin_amdgcn_cvt_pk_fp8_f32(e[10], e[11], wC, true);        \
          u32 wD = __builtin_amdgcn_cvt_pk_fp8_f32(e[12], e[13], 0, false);    \
          wD = __builtin_amdgcn_cvt_pk_fp8_f32(e[14], e[15], wD, true);        \
          asm("v_permlane32_swap_b32 %0, %1" : "+v"(wA), "+v"(wB));            \
          asm("v_permlane32_swap_b32 %0, %1" : "+v"(wC), "+v"(wD));            \
          u64x2 ev;                                                            \
          ev[0] = ((unsigned long)wB << 32) | wA;                              \
          ev[1] = ((unsigned long)wD << 32) | wC;                              \
          *(u64x2*)(&ebuf[j_ & 1][u][mfp * 1024 + l * 16]) = ev;               \
        }                                                                      \
      }                                                                        \
    } else {                                                                   \
      if (j_ < KJ) V_ISSUE(NXT, 2 * j_)                                        \
      if (j_ > 0) {                                                            \
        __builtin_amdgcn_s_setprio(1);                                         \
        PV_U(&ebuf[(j_ - 1) & 1][0][l * 16], CUR##A0, CUR##B0)                 \
        PV_U(&ebuf[(j_ - 1) & 1][1][l * 16], CUR##A1, CUR##B1)                 \
        __builtin_amdgcn_s_setprio(0);                                         \
      }                                                                        \
    }                                                                          \
    if (j_ < KJ) __syncthreads();                                              \
  }

__global__ __launch_bounds__(512) void k_attn_out(
    const unsigned short* __restrict__ Qt, const unsigned short* __restrict__ Kt,
    const unsigned char* __restrict__ V8,
    const float* __restrict__ cbias,
    unsigned short* __restrict__ pout,
    int nsplit, int nlen)
{
  __shared__ __align__(16) char qbuf[2][2][2048];  // [buf][u] Q frag-linear
  __shared__ __align__(16) char ebuf[2][2][4096];  // [buf][u] E A-frags [mf][lane][16B]

  const int wg = (int)blockIdx.x;
  const int chunk = (int)gridDim.x >> 3;           // blocks per XCD (bijective)
  const int id2 = (wg & 7) * chunk + (wg >> 3);
  const int per_b = 32 * nsplit;                   // m-tiles(128) per batch * nsplit
  const int b = id2 / per_b;
  const int rem = id2 - b * per_b;
  const int ns = rem >> 5;
  const int m0 = (rem & 31) * 128;
  const int nbeg = ns * nlen;

  const int t = threadIdx.x;
  const int w = t >> 6, l = t & 63, h = l >> 5, col = l & 31;
  const int mfp = w & 3;                           // producer m-frag
  const int ccons = (w & 3) * 64;                  // consumer c-quarter

  const unsigned short* Kb = Kt + (size_t)b * NN * 32;
  const float* cb = cbias + (size_t)b * NN + nbeg;

  // producer K fragments (B operand of S), loop-invariant
  bf16x8 bk0 = ld_frag(Kb + (size_t)(m0 + 32 * mfp + col) * 32 + 8 * h);
  bf16x8 bk1 = ld_frag(Kb + (size_t)(m0 + 32 * mfp + col) * 32 + 16 + 8 * h);

  // Q staging: per tile 128 chunks of 16B; all 8 waves, lanes 0-15.
  const int ll = l & 15;
  const size_t gqoff = (size_t)(((w & 1) * 16 + ll) * 64 + ((w >> 1) & 1) * 16
                                + (w >> 2) * 32);
  const char* qsrc = (const char*)Qt + ((size_t)b * NN + nbeg) * 64 + gqoff;

  // consumer V base: V8[b][nt][kh=h][c=ccons+col][16B]; per tile += 8192
  const char* vg = (const char*)V8
      + (((size_t)b * 128 + (nbeg >> 5)) * 2 + h) * 4096
      + (size_t)(ccons + col) * 16;

  f32x16 acc[4][2];
#pragma unroll
  for (int mf = 0; mf < 4; ++mf)
#pragma unroll
    for (int cf = 0; cf < 2; ++cf) acc[mf][cf] = zero16();

  u64x2 S0A0, S0B0, S0A1, S0B1;   // V reg set 0
  u64x2 S1A0, S1B0, S1A1, S1B1;   // V reg set 1
  S0A0 = S0B0 = S0A1 = S0B1 = (u64x2)0;
  S1A0 = S1B0 = S1A1 = S1B1 = (u64x2)0;

  const int KJ = nlen >> 6;                        // intervals of 64 n (32)

  // ---- prologue: stage Q interval 0 ----
  if (ll == l) {
    gload16(qsrc, &qbuf[0][0][w * 256]);
    gload16(qsrc + 2048, &qbuf[0][1][w * 256]);
  }
  __syncthreads();

  for (int jj = 0; jj <= KJ; jj += 2) {
    K3_ITER(jj,     S0, S1)      // iter even: PV uses set0, issues set1
    K3_ITER(jj + 1, S1, S0)      // iter odd : PV uses set1, issues set0
  }

  // ---- consumer epilogue: write bf16 D tiles [m][c]-major ----
  if (w >= 4) {
    unsigned short* pb = pout + (((size_t)ns * NB + b) * NN + m0) * CC + ccons;
#pragma unroll
    for (int mf = 0; mf < 4; ++mf)
#pragma unroll
      for (int cf = 0; cf < 2; ++cf)
#pragma unroll
        for (int r = 0; r < 16; ++r) {
          int mloc = 32 * mf + (r & 3) + 8 * (r >> 2) + 4 * h;
          pb[(size_t)mloc * CC + 32 * cf + col] = f2bf(acc[mf][cf][r]);
        }
  }
}

// ---------------- Kernel 4: combine + transpose + residual ----------------
__global__ __launch_bounds__(256) void k_comb(
    const unsigned short* __restrict__ pout, const float* __restrict__ x,
    const float* __restrict__ gamma, float* __restrict__ out, int nsplit)
{
  __shared__ float ld[64][65];
  const size_t STRIDE = (size_t)NB * CC * NN;
  const int t = threadIdx.x;
  const int m0 = blockIdx.x * 64, c0 = blockIdx.y * 64, b = blockIdx.z;
  const int ci = t & 63, mo = t >> 6;

  const unsigned short* pb = pout + ((size_t)b * NN + m0) * CC + c0;
#pragma unroll
  for (int rep = 0; rep < 16; ++rep) {
    const int mi = 4 * rep + mo;
    float s = bf2f(pb[(size_t)mi * CC + ci]);
    for (int ns = 1; ns < nsplit; ++ns)
      s += bf2f(pb[ns * STRIDE + (size_t)mi * CC + ci]);
    ld[mi][ci] = s;
  }
  __syncthreads();

  const float g = gamma[0];
  const int mi2 = t & 63;
#pragma unroll
  for (int rep = 0; rep < 16; ++rep) {
    const int cj = 4 * rep + mo;
    const size_t idx = ((size_t)b * CC + c0 + cj) * NN + m0 + mi2;
    out[idx] = g * ld[mi2][cj] + x[idx];
  }
}

// ---------------- launch ---------------------------------------------------
extern "C" void kernel_launch(void* const* d_in, const int* in_sizes, int n_in,
                              void* d_out, int out_size, void* d_ws, size_t ws_size,
                              hipStream_t stream) {
  const float* x     = (const float*)d_in[0];
  const float* Wq    = (const float*)d_in[1];
  const float* bq    = (const float*)d_in[2];
  const float* Wk    = (const float*)d_in[3];
  const float* bk    = (const float*)d_in[4];
  const float* Wv    = (const float*)d_in[5];
  const float* bv    = (const float*)d_in[6];
  const float* gamma = (const float*)d_in[7];
  float* out = (float*)d_out;

  char* ws = (char*)d_ws;
  unsigned short* Qt = (unsigned short*)(ws);                      // 1 MB
  unsigned short* Kt = (unsigned short*)(ws + (1u << 20));         // 1 MB
  unsigned char*  V8 = (unsigned char*)(ws + (2u << 20));          // 4 MB
  unsigned short* Wb = (unsigned short*)(ws + (6u << 20));         // 160 KB
  float* cbias = (float*)(ws + (10u << 20) + (2u << 18));          // 64 KB
  const size_t POUT_OFF = (11u << 20);
  unsigned short* pout = (unsigned short*)(ws + POUT_OFF);
  const size_t PART_BYTES = (size_t)NB * CC * NN * 2;              // 8.4 MB (bf16)

  int nsplit = (ws_size >= POUT_OFF + 2 * PART_BYTES) ? 2 : 1;

  k_wcvt<<<dim3(80), 256, 0, stream>>>(Wq, Wk, Wv, Wb);
  k_proj<<<dim3(NN / 32, NB), 256, 0, stream>>>(x, Wb, bq, bk, bv, Qt, Kt, V8);
  k_rowstats<<<dim3(NN / 64, NB), 512, 0, stream>>>(Qt, Kt, cbias);
  k_attn_out<<<dim3(128 * nsplit), 512, 0, stream>>>(
      Qt, Kt, V8, cbias, pout, nsplit, NN / nsplit);
  k_comb<<<dim3(NN / 64, CC / 64, NB), 256, 0, stream>>>(pout, x, gamma, out, nsplit);
}